// Round 2
// baseline (190.419 us; speedup 1.0000x reference)
//
#include <hip/hip_runtime.h>

#define NA      286   // atoms
#define CIN     23
#define NKH     100   // radial hidden width
#define BATCH   32
#define NB_PAD  320   // b padded to 5 tiles of 64
#define TB      64    // b tile width (= lanes)
#define ATILE   12    // a's per block (6 per wave, 2 waves)
#define APW     6     // a's per wave
#define NTILE_A 24    // ceil(286/12)
#define NTILE_B 5

#define Y0F      0.28209479177387814f   // 1/(2 sqrt(pi))
#define RSQRT_N  0.05913123960994873f   // 1/sqrt(286)

// cos((pi/2)*x) for |x| <= 1; Taylor to t^10, |err| <= ~5e-7
__device__ __forceinline__ float cos_half_pi(float x) {
    float t = 1.5707963267948966f * x;
    float w = t * t;
    return 1.f + w * (-0.5f + w * (4.16666667e-2f + w * (-1.38888889e-3f
               + w * (2.48015873e-5f - w * 2.75573192e-7f))));
}

// ---------------------------------------------------------------------------
// Kernel 1: c[z][k][b] = Y0 * sum_j rW2[k][j] * features[z][b][j]; pad b -> 0
//           block 0 also packs wk4[k] = (W1[0,k], W1[1,k], W1[2,k], b1[k])
// ---------------------------------------------------------------------------
__global__ void __launch_bounds__(256) prep_kernel(
    const float* __restrict__ feat,   // [B][286][23]
    const float* __restrict__ rW2,    // [100][23]
    const float* __restrict__ rW1,    // [3][100]
    const float* __restrict__ rb1,    // [100]
    float* __restrict__ cbuf,         // [B][100][320]
    float* __restrict__ wk4)          // [100][4]
{
    if (blockIdx.x == 0 && threadIdx.x < NKH) {
        int k = threadIdx.x;
        wk4[4 * k + 0] = rW1[k];
        wk4[4 * k + 1] = rW1[NKH + k];
        wk4[4 * k + 2] = rW1[2 * NKH + k];
        wk4[4 * k + 3] = rb1[k];
    }
    int gid = blockIdx.x * 256 + threadIdx.x;
    int b   = gid % NB_PAD;
    int rem = gid / NB_PAD;
    int k   = rem % NKH;
    int z   = rem / NKH;
    if (z >= BATCH) return;
    float val = 0.f;
    if (b < NA) {
        const float* fp = feat + ((size_t)z * NA + b) * CIN;
        const float* wp = rW2 + k * CIN;
        float s = 0.f;
#pragma unroll
        for (int j = 0; j < CIN; ++j) s = fmaf(wp[j], fp[j], s);
        val = s * Y0F;
    }
    cbuf[((size_t)z * NKH + k) * NB_PAD + b] = val;
}

// ---------------------------------------------------------------------------
// Kernel 2: feats[z][a] = rsqrtN * sum_b sum_k relu(basis(r_ab)@rW1 + rb1)_k
//                                               * c[z][b][k]
// block = 128 thr (2 waves, 6 a's each); grid = (24 a-tiles, 32 z); lane = b
// k-loop: 1 s_load_dwordx4 (uniform W) + 1 conflict-free ds_read_b32 + 30 VALU
// ---------------------------------------------------------------------------
__global__ void __launch_bounds__(128) pair_kernel(
    const float* __restrict__ geom,   // [B][286][3]
    const float* __restrict__ cbuf,   // [B][100][320]
    const float* __restrict__ wk4,    // [100][4]
    float* __restrict__ feats)        // [B][288]
{
    __shared__ float c_lds[NKH * TB];   // 25600 B
    __shared__ float ga[ATILE * 3];     // a-geometry for this block

    const int tid   = threadIdx.x;
    const int z     = blockIdx.y;
    const int aBase = blockIdx.x * ATILE;

    if (tid < ATILE * 3) {
        int aa = aBase + tid / 3;
        int d  = tid - 3 * (tid / 3);
        ga[tid] = (aa < NA) ? geom[((size_t)z * NA + aa) * 3 + d] : 0.f;
    }

    const int wave = tid >> 6;
    const int lane = tid & 63;

    float acc[APW];
#pragma unroll
    for (int i = 0; i < APW; ++i) acc[i] = 0.f;

    const float* csrc = cbuf + (size_t)z * NKH * NB_PAD;
    const float4* wkv = (const float4*)wk4;

    for (int t = 0; t < NTILE_B; ++t) {
        const int b0 = t * TB;
        // ---- stage c tile [100 k][64 b]: coalesced float4 global -> LDS ----
        for (int i = tid; i < NKH * (TB / 4); i += 128) {
            int row = i >> 4;
            int col = (i & 15) << 2;
            float4 v = *(const float4*)(csrc + (size_t)row * NB_PAD + b0 + col);
            c_lds[row * TB + col + 0] = v.x;
            c_lds[row * TB + col + 1] = v.y;
            c_lds[row * TB + col + 2] = v.z;
            c_lds[row * TB + col + 3] = v.w;
        }
        // lane's b geometry (padded b -> c=0 kills contribution; geom value moot)
        const int b = b0 + lane;
        float gbx = 0.f, gby = 0.f, gbz = 0.f;
        if (b < NA) {
            const float* g = geom + ((size_t)z * NA + b) * 3;
            gbx = g[0]; gby = g[1]; gbz = g[2];
        }
        __syncthreads();

        // basis u[a][0..2] for this wave's 6 a's vs this lane's b
        float u0[APW], u1[APW], u2[APW];
#pragma unroll
        for (int i = 0; i < APW; ++i) {
            const float* gp = &ga[(wave * APW + i) * 3];
            float dx = gbx - gp[0], dy = gby - gp[1], dz = gbz - gp[2];
            float r  = sqrtf(fmaf(dx, dx, fmaf(dy, dy, fmaf(dz, dz, 1e-12f))));
            float zz = r * (1.f / 1.5f);            // >= 0
            u0[i] = cos_half_pi(fminf(zz, 1.f));
            u1[i] = cos_half_pi(fminf(fmaxf(zz - 1.f, -1.f), 1.f));
            u2[i] = cos_half_pi(fminf(fmaxf(zz - 2.f, -1.f), 1.f));
        }

        // ---- k loop ----
#pragma unroll 4
        for (int k = 0; k < NKH; ++k) {
            int ku = __builtin_amdgcn_readfirstlane(k);   // force scalar load path
            float4 w  = wkv[ku];
            float  cb = c_lds[(k << 6) | lane];
#pragma unroll
            for (int i = 0; i < APW; ++i) {
                float s = fmaf(u0[i], w.x, fmaf(u1[i], w.y, fmaf(u2[i], w.z, w.w)));
                acc[i] = fmaf(fmaxf(s, 0.f), cb, acc[i]);
            }
        }
        __syncthreads();
    }

    // wave-level reduction over lanes (b) and store
#pragma unroll
    for (int i = 0; i < APW; ++i) {
        float v = acc[i];
        for (int off = 32; off; off >>= 1) v += __shfl_xor(v, off);
        if (lane == 0) {
            int a = aBase + wave * APW + i;
            if (a < NA) feats[z * 288 + a] = v * RSQRT_N;
        }
    }
}

// ---------------------------------------------------------------------------
// Kernel 3: rb2 constant term + 286->30->10->1 MLP head; 1 wave per z
// ---------------------------------------------------------------------------
__global__ void __launch_bounds__(64) head_kernel(
    const float* __restrict__ feats,    // [B][288]
    const float* __restrict__ featIn,   // [B][286][23]
    const float* __restrict__ rb2,      // [23]
    const float* __restrict__ fc1W, const float* __restrict__ fc1b,
    const float* __restrict__ fc2W, const float* __restrict__ fc2b,
    const float* __restrict__ fc3W, const float* __restrict__ fc3b,
    float* __restrict__ out)            // [B][1]
{
    __shared__ float rb2f[CIN];
    __shared__ float h1[30];
    __shared__ float h2[10];
    const int z = blockIdx.x;
    const int lane = threadIdx.x;

    if (lane < CIN) rb2f[lane] = rb2[lane];
    __syncthreads();

    // constant term: Y0/sqrt(N) * sum_b sum_j rb2[j]*f[z,b,j]
    float partial = 0.f;
    for (int b = lane; b < NA; b += 64) {
        const float* fp = featIn + ((size_t)z * NA + b) * CIN;
#pragma unroll
        for (int j = 0; j < CIN; ++j) partial = fmaf(fp[j], rb2f[j], partial);
    }
    for (int off = 32; off; off >>= 1) partial += __shfl_xor(partial, off);
    const float cz = partial * (Y0F * RSQRT_N);

    if (lane < 30) {
        float o = fc1b[lane];
        const float* fz = feats + z * 288;
        for (int a = 0; a < NA; ++a)
            o = fmaf(fz[a] + cz, fc1W[a * 30 + lane], o);
        h1[lane] = fmaxf(o, 0.f);
    }
    __syncthreads();
    if (lane < 10) {
        float o = fc2b[lane];
#pragma unroll
        for (int t = 0; t < 30; ++t) o = fmaf(h1[t], fc2W[t * 10 + lane], o);
        h2[lane] = fmaxf(o, 0.f);
    }
    __syncthreads();
    if (lane == 0) {
        float o = fc3b[0];
#pragma unroll
        for (int t = 0; t < 10; ++t) o = fmaf(h2[t], fc3W[t], o);
        out[z] = o;
    }
}

// ---------------------------------------------------------------------------
extern "C" void kernel_launch(void* const* d_in, const int* in_sizes, int n_in,
                              void* d_out, int out_size, void* d_ws, size_t ws_size,
                              hipStream_t stream) {
    // reference dtypes are float32 throughout (setup_inputs uses jnp.float32)
    const float* features = (const float*)d_in[1];
    const float* geometry = (const float*)d_in[2];
    const float* rW1  = (const float*)d_in[3];
    const float* rb1  = (const float*)d_in[4];
    const float* rW2  = (const float*)d_in[5];
    const float* rb2  = (const float*)d_in[6];
    const float* fc1W = (const float*)d_in[7];
    const float* fc1b = (const float*)d_in[8];
    const float* fc2W = (const float*)d_in[9];
    const float* fc2b = (const float*)d_in[10];
    const float* fc3W = (const float*)d_in[11];
    const float* fc3b = (const float*)d_in[12];

    float* cbuf  = (float*)d_ws;                         // 32*100*320 f32 = 4.096 MB
    float* feats = cbuf + (size_t)BATCH * NKH * NB_PAD;  // 32*288 f32
    float* wk4   = feats + (size_t)BATCH * 288;          // 100*4 f32

    float* out = (float*)d_out;

    prep_kernel<<<dim3((BATCH * NKH * NB_PAD + 255) / 256), 256, 0, stream>>>(
        features, rW2, rW1, rb1, cbuf, wk4);
    pair_kernel<<<dim3(NTILE_A, BATCH), 128, 0, stream>>>(
        geometry, cbuf, wk4, feats);
    head_kernel<<<BATCH, 64, 0, stream>>>(
        feats, features, rb2, fc1W, fc1b, fc2W, fc2b, fc3W, fc3b, out);
}

// Round 3
// 173.659 us; speedup vs baseline: 1.0965x; 1.0965x over previous
//
#include <hip/hip_runtime.h>

#define NA      286   // atoms
#define CIN     23
#define NKH     100   // radial hidden width
#define KHALF   50    // k per block (k-split 2)
#define BATCH   32
#define NB_PAD  320   // b padded to 5 tiles of 64
#define TB      64    // b tile width (= lanes)
#define ATILE   12    // a's per block (3 per wave, 4 waves)
#define APW     3
#define NTILE_A 24    // ceil(286/12)
#define NTILE_B 5

#define Y0F      0.28209479177387814f   // 1/(2 sqrt(pi))
#define RSQRT_N  0.05913123960994873f   // 1/sqrt(286)

// cos((pi/2)*x) for |x| <= 1; Taylor to t^10, |err| <= ~5e-7
__device__ __forceinline__ float cos_half_pi(float x) {
    float t = 1.5707963267948966f * x;
    float w = t * t;
    return 1.f + w * (-0.5f + w * (4.16666667e-2f + w * (-1.38888889e-3f
               + w * (2.48015873e-5f - w * 2.75573192e-7f))));
}

// ---------------------------------------------------------------------------
// Kernel 1: c[z][k][b] = Y0 * sum_j rW2[k][j] * feat[z][b][j]   (b padded -> 0)
// grid (NTILE_B*4, BATCH): bT = bx%5 (64 b's), kQ = bx/5 (25 k's)
// feat tile staged via LDS (contiguous coalesced); rW2 row uniform -> s_load.
// Block (0,0) also packs wk4[k] = (W1[0,k], W1[1,k], W1[2,k], b1[k]).
// ---------------------------------------------------------------------------
__global__ void __launch_bounds__(256) prep_kernel(
    const float* __restrict__ feat,   // [B][286][23]
    const float* __restrict__ rW2,    // [100][23]
    const float* __restrict__ rW1,    // [3][100]
    const float* __restrict__ rb1,    // [100]
    float* __restrict__ cbuf,         // [B][100][320]
    float4* __restrict__ wk4)         // [100]
{
    __shared__ float flds[TB * CIN];  // 5888 B
    const int tid = threadIdx.x;
    const int bT  = blockIdx.x % NTILE_B;
    const int kQ  = blockIdx.x / NTILE_B;
    const int z   = blockIdx.y;

    if (blockIdx.x == 0 && blockIdx.y == 0 && tid < NKH)
        wk4[tid] = make_float4(rW1[tid], rW1[NKH + tid], rW1[2 * NKH + tid], rb1[tid]);

    const int b0   = bT * TB;
    const int rows = (NA - b0 < TB) ? (NA - b0) : TB;
    const int nf   = rows * CIN;
    const float* src = feat + ((size_t)z * NA + b0) * CIN;   // contiguous
    for (int i = tid; i < TB * CIN; i += 256)
        flds[i] = (i < nf) ? src[i] : 0.f;
    __syncthreads();

    for (int o = tid; o < TB * (NKH / 4); o += 256) {        // 64 b x 25 k
        int b  = o & 63;
        int k  = kQ * (NKH / 4) + (o >> 6);                  // uniform per wave
        const float* wp = rW2 + k * CIN;
        float s = 0.f;
#pragma unroll
        for (int j = 0; j < CIN; ++j) s = fmaf(flds[b * CIN + j], wp[j], s);
        cbuf[((size_t)z * NKH + k) * NB_PAD + b0 + b] = s * Y0F;
    }
}

// ---------------------------------------------------------------------------
// Kernel 2: partial[kh][z][a] = sum_b sum_{k in half} relu(u(a,b)@w_k) * c[z][b][k]
// grid (24, 32, 2); block 256 (4 waves x 3 a); lane = b within 64-tile
// k-loop per k: 1 broadcast float4 (LDS) + 1 conflict-free ds_read_b32 + 15 VALU
// ---------------------------------------------------------------------------
__global__ void __launch_bounds__(256) pair_kernel(
    const float* __restrict__ geom,      // [B][286][3]
    const float* __restrict__ cbuf,      // [B][100][320]
    const float4* __restrict__ wk4,      // [100]
    float* __restrict__ feats_part)      // [2][B][288]
{
    __shared__ float  c_lds[KHALF * TB];  // 12800 B
    __shared__ float4 wl[KHALF];          // 800 B
    __shared__ float  ga[ATILE * 3];      // 144 B

    const int tid   = threadIdx.x;
    const int z     = blockIdx.y;
    const int kh    = blockIdx.z;
    const int aBase = blockIdx.x * ATILE;

    if (tid < KHALF) wl[tid] = wk4[kh * KHALF + tid];
    if (tid >= 64 && tid < 64 + ATILE * 3) {
        int t  = tid - 64;
        int aa = aBase + t / 3;
        int d  = t - 3 * (t / 3);
        ga[t] = (aa < NA) ? geom[((size_t)z * NA + aa) * 3 + d] : 0.f;
    }

    const int wave = tid >> 6;
    const int lane = tid & 63;

    float acc[APW] = {0.f, 0.f, 0.f};
    const float* csrc = cbuf + ((size_t)z * NKH + kh * KHALF) * NB_PAD;

    for (int t = 0; t < NTILE_B; ++t) {
        const int b0 = t * TB;
        // stage c tile [50 k][64 b]: coalesced float4 global -> LDS
        for (int i = tid; i < KHALF * (TB / 4); i += 256) {
            int row = i >> 4;
            int col = (i & 15) << 2;
            float4 v = *(const float4*)(csrc + (size_t)row * NB_PAD + b0 + col);
            c_lds[row * TB + col + 0] = v.x;
            c_lds[row * TB + col + 1] = v.y;
            c_lds[row * TB + col + 2] = v.z;
            c_lds[row * TB + col + 3] = v.w;
        }
        const int b = b0 + lane;
        float gbx = 0.f, gby = 0.f, gbz = 0.f;
        if (b < NA) {
            const float* g = geom + ((size_t)z * NA + b) * 3;
            gbx = g[0]; gby = g[1]; gbz = g[2];
        }
        __syncthreads();

        // basis for this wave's 3 a's vs this lane's b
        float u0[APW], u1[APW], u2[APW];
#pragma unroll
        for (int i = 0; i < APW; ++i) {
            const float* gp = &ga[(wave * APW + i) * 3];
            float dx = gbx - gp[0], dy = gby - gp[1], dz = gbz - gp[2];
            float r  = sqrtf(fmaf(dx, dx, fmaf(dy, dy, fmaf(dz, dz, 1e-12f))));
            float zz = r * (1.f / 1.5f);            // >= 0
            u0[i] = cos_half_pi(fminf(zz, 1.f));
            u1[i] = cos_half_pi(fminf(fmaxf(zz - 1.f, -1.f), 1.f));
            u2[i] = cos_half_pi(fminf(fmaxf(zz - 2.f, -1.f), 1.f));
        }

        // k loop over this half
#pragma unroll 10
        for (int k = 0; k < KHALF; ++k) {
            float4 w  = wl[k];                       // uniform-address broadcast
            float  cb = c_lds[(k << 6) | lane];      // 2-way alias = free
#pragma unroll
            for (int i = 0; i < APW; ++i) {
                float s = fmaf(u0[i], w.x, fmaf(u1[i], w.y, fmaf(u2[i], w.z, w.w)));
                acc[i] = fmaf(fmaxf(s, 0.f), cb, acc[i]);
            }
        }
        __syncthreads();
    }

    // wave-level reduction over lanes (b) and store partial
#pragma unroll
    for (int i = 0; i < APW; ++i) {
        float v = acc[i];
        for (int off = 32; off; off >>= 1) v += __shfl_xor(v, off);
        if (lane == 0) {
            int a = aBase + wave * APW + i;
            if (a < NA) feats_part[((size_t)kh * BATCH + z) * 288 + a] = v * RSQRT_N;
        }
    }
}

// ---------------------------------------------------------------------------
// Kernel 3: rb2 constant + sum both k-halves + 286->30->10->1 MLP head
// 1 wave per z; fc1 a-range split across lane halves, combined via shfl_xor(32)
// ---------------------------------------------------------------------------
__global__ void __launch_bounds__(64) head_kernel(
    const float* __restrict__ featsP,   // [2][B][288]
    const float* __restrict__ featIn,   // [B][286][23]
    const float* __restrict__ rb2,      // [23]
    const float* __restrict__ fc1W, const float* __restrict__ fc1b,
    const float* __restrict__ fc2W, const float* __restrict__ fc2b,
    const float* __restrict__ fc3W, const float* __restrict__ fc3b,
    float* __restrict__ out)            // [B][1]
{
    __shared__ float rb2f[CIN];
    __shared__ float h1[30];
    __shared__ float h2[10];
    const int z = blockIdx.x;
    const int lane = threadIdx.x;

    if (lane < CIN) rb2f[lane] = rb2[lane];
    __syncthreads();

    // constant term: Y0/sqrt(N) * sum_b sum_j rb2[j]*f[z,b,j]
    float partial = 0.f;
    for (int b = lane; b < NA; b += 64) {
        const float* fp = featIn + ((size_t)z * NA + b) * CIN;
#pragma unroll
        for (int j = 0; j < CIN; ++j) partial = fmaf(fp[j], rb2f[j], partial);
    }
    for (int off = 32; off; off >>= 1) partial += __shfl_xor(partial, off);
    const float cz = partial * (Y0F * RSQRT_N);

    // fc1: lanes j and j+32 split the a-range, combine with shfl_xor(32)
    const int half = lane >> 5;
    const int j    = lane & 31;
    float o = 0.f;
    if (j < 30) {
        const float* f0 = featsP + (size_t)z * 288;
        const float* f1 = featsP + ((size_t)BATCH + z) * 288;
        int a0 = half ? 143 : 0;
        int a1 = half ? NA : 143;
        for (int a = a0; a < a1; ++a)
            o = fmaf(f0[a] + f1[a] + cz, fc1W[a * 30 + j], o);
    }
    o += __shfl_xor(o, 32);
    if (lane < 30) h1[lane] = fmaxf(o + fc1b[lane], 0.f);
    __syncthreads();

    if (lane < 10) {
        float v = fc2b[lane];
#pragma unroll
        for (int t = 0; t < 30; ++t) v = fmaf(h1[t], fc2W[t * 10 + lane], v);
        h2[lane] = fmaxf(v, 0.f);
    }
    __syncthreads();
    if (lane == 0) {
        float v = fc3b[0];
#pragma unroll
        for (int t = 0; t < 10; ++t) v = fmaf(h2[t], fc3W[t], v);
        out[z] = v;
    }
}

// ---------------------------------------------------------------------------
extern "C" void kernel_launch(void* const* d_in, const int* in_sizes, int n_in,
                              void* d_out, int out_size, void* d_ws, size_t ws_size,
                              hipStream_t stream) {
    const float* features = (const float*)d_in[1];
    const float* geometry = (const float*)d_in[2];
    const float* rW1  = (const float*)d_in[3];
    const float* rb1  = (const float*)d_in[4];
    const float* rW2  = (const float*)d_in[5];
    const float* rb2  = (const float*)d_in[6];
    const float* fc1W = (const float*)d_in[7];
    const float* fc1b = (const float*)d_in[8];
    const float* fc2W = (const float*)d_in[9];
    const float* fc2b = (const float*)d_in[10];
    const float* fc3W = (const float*)d_in[11];
    const float* fc3b = (const float*)d_in[12];

    float* cbuf   = (float*)d_ws;                          // 32*100*320 = 4.096 MB
    float* featsP = cbuf + (size_t)BATCH * NKH * NB_PAD;   // 2*32*288 f32
    float* wk4    = featsP + 2 * (size_t)BATCH * 288;      // 100*4 f32

    float* out = (float*)d_out;

    prep_kernel<<<dim3(NTILE_B * 4, BATCH), 256, 0, stream>>>(
        features, rW2, rW1, rb1, cbuf, (float4*)wk4);
    pair_kernel<<<dim3(NTILE_A, BATCH, 2), 256, 0, stream>>>(
        geometry, cbuf, (const float4*)wk4, featsP);
    head_kernel<<<BATCH, 64, 0, stream>>>(
        featsP, features, rb2, fc1W, fc1b, fc2W, fc2b, fc3W, fc3b, out);
}

// Round 5
// 144.398 us; speedup vs baseline: 1.3187x; 1.2026x over previous
//
#include <hip/hip_runtime.h>

#define NA      286   // atoms
#define CIN     23
#define NKH     100   // radial hidden width
#define NKP     50    // k-pairs
#define KPH     25    // k-pairs per half (k-split 2)
#define BATCH   32
#define NB_PAD  320
#define TB      64
#define ATILE   12    // a's per block (3 per wave, 4 waves)
#define APW     3
#define NTILE_A 24
#define NTILE_B 5

#define Y0F      0.28209479177387814f   // 1/(2 sqrt(pi))
#define RSQRT_N  0.05913123960994873f   // 1/sqrt(286)

typedef _Float16 h2v __attribute__((ext_vector_type(2)));
union F4H { float4 f; h2v h[4]; };

__device__ __forceinline__ h2v h2_splat(float x) {
    _Float16 v = (_Float16)x;
    h2v r; r.x = v; r.y = v; return r;
}
__device__ __forceinline__ h2v h2_pack(float a, float b) {
    h2v r; r.x = (_Float16)a; r.y = (_Float16)b; return r;
}
__device__ __forceinline__ h2v h2_fma(h2v a, h2v b, h2v c) {
#if __has_builtin(__builtin_elementwise_fma)
    return __builtin_elementwise_fma(a, b, c);
#else
    return a * b + c;
#endif
}
__device__ __forceinline__ h2v h2_max0(h2v a) {
    h2v z; z.x = (_Float16)0.f; z.y = (_Float16)0.f;
#if __has_builtin(__builtin_elementwise_max)
    return __builtin_elementwise_max(a, z);
#else
    h2v r; r.x = a.x > z.x ? a.x : z.x; r.y = a.y > z.y ? a.y : z.y; return r;
#endif
}
__device__ __forceinline__ float fdot2f(h2v a, h2v b, float c) {
#if __has_builtin(__builtin_amdgcn_fdot2)
    return __builtin_amdgcn_fdot2(a, b, c, false);
#else
    return c + (float)a.x * (float)b.x + (float)a.y * (float)b.y;
#endif
}

// cos((pi/2)*x) for |x| <= 1; |err| <= ~3e-5 (way under fp16 noise)
__device__ __forceinline__ float cos_half_pi(float x) {
    float t = 1.5707963267948966f * x;
    float w = t * t;
    return 1.f + w * (-0.5f + w * (4.16666667e-2f + w * (-1.38888889e-3f
               + w * 2.48015873e-5f)));
}

// ---------------------------------------------------------------------------
// Kernel 1: cbuf2[z][kp][b] = h2( Y0*dot(rW2[2kp],f[z,b]), Y0*dot(rW2[2kp+1],f[z,b]) )
// grid (5 bT, 32 z, 2 kh); 256 thr; lane = b, waves stride kp.
// Block (0,0,0) also packs wpk[kp] = 4x h2 {W1[0,k0|k1], W1[1,..], W1[2,..], b1[..]}
// ---------------------------------------------------------------------------
__global__ void __launch_bounds__(256) prep_kernel(
    const float* __restrict__ feat,   // [B][286][23]
    const float* __restrict__ rW2,    // [100][23]
    const float* __restrict__ rW1,    // [3][100]
    const float* __restrict__ rb1,    // [100]
    h2v* __restrict__ cbuf2,          // [B][50][320]
    float4* __restrict__ wpk)         // [50]
{
    __shared__ float rlds[2 * KPH * CIN];   // 50 k x 23 = 4600 B
    const int tid = threadIdx.x;
    const int bT  = blockIdx.x;
    const int z   = blockIdx.y;
    const int kh  = blockIdx.z;

    if (bT == 0 && z == 0 && kh == 0 && tid < NKP) {
        int k0 = 2 * tid, k1 = k0 + 1;
        F4H u;
        u.h[0] = h2_pack(rW1[k0],           rW1[k1]);
        u.h[1] = h2_pack(rW1[NKH + k0],     rW1[NKH + k1]);
        u.h[2] = h2_pack(rW1[2 * NKH + k0], rW1[2 * NKH + k1]);
        u.h[3] = h2_pack(rb1[k0],           rb1[k1]);
        wpk[tid] = u.f;
    }

    const float* rsrc = rW2 + (size_t)kh * (NKH / 2) * CIN;
    for (int i = tid; i < 2 * KPH * CIN; i += 256) rlds[i] = rsrc[i];

    const int lane = tid & 63, wave = tid >> 6;
    const int b = bT * TB + lane;
    float f[CIN];
    if (b < NA) {
        const float* fp = feat + ((size_t)z * NA + b) * CIN;
#pragma unroll
        for (int j = 0; j < CIN; ++j) f[j] = fp[j];
    } else {
#pragma unroll
        for (int j = 0; j < CIN; ++j) f[j] = 0.f;
    }
    __syncthreads();

    for (int kp = wave; kp < KPH; kp += 4) {
        const float* w0 = &rlds[(2 * kp) * CIN];
        const float* w1 = &rlds[(2 * kp + 1) * CIN];
        float s0 = 0.f, s1 = 0.f;
#pragma unroll
        for (int j = 0; j < CIN; ++j) {
            s0 = fmaf(f[j], w0[j], s0);
            s1 = fmaf(f[j], w1[j], s1);
        }
        cbuf2[((size_t)z * NKP + kh * KPH + kp) * NB_PAD + bT * TB + lane] =
            h2_pack(s0 * Y0F, s1 * Y0F);
    }
}

// ---------------------------------------------------------------------------
// Kernel 2: partial[kh][z][a] = sum_b sum_{kp in half} dot2(relu(u@W), c)
// grid (24, 32, 2); 256 thr (4 waves x 3 a); lane = b within 64-tile
// per kp per wave: 1 ds_read_b128 (uniform W) + 1 ds_read_b32 (c, 2-way free)
//                  + 9 pk_fma + 3 pk_max + 3 dot2  (15 VALU for 2 k x 3 a)
// ---------------------------------------------------------------------------
__global__ void __launch_bounds__(256) pair_kernel(
    const float* __restrict__ geom,      // [B][286][3]
    const h2v* __restrict__ cbuf2,       // [B][50][320]
    const float4* __restrict__ wpk,      // [50]
    float* __restrict__ feats_part)      // [2][B][288]
{
    __shared__ h2v    c_lds[KPH * TB];   // 6400 B
    __shared__ float4 wl[KPH];           // 400 B
    __shared__ float  ga[ATILE * 3];

    const int tid   = threadIdx.x;
    const int z     = blockIdx.y;
    const int kh    = blockIdx.z;
    const int aBase = blockIdx.x * ATILE;

    if (tid < KPH) wl[tid] = wpk[kh * KPH + tid];
    if (tid >= 64 && tid < 64 + ATILE * 3) {
        int t  = tid - 64;
        int aa = aBase + t / 3;
        int d  = t - 3 * (t / 3);
        ga[t] = (aa < NA) ? geom[((size_t)z * NA + aa) * 3 + d] : 0.f;
    }

    const int wave = tid >> 6;
    const int lane = tid & 63;

    float acc[APW] = {0.f, 0.f, 0.f};
    const h2v* csrc = cbuf2 + ((size_t)z * NKP + kh * KPH) * NB_PAD;

    for (int t = 0; t < NTILE_B; ++t) {
        const int b0 = t * TB;
        // stage c tile [25 kp][64 b] as uint4 (coalesced, 16B-aligned)
        for (int i = tid; i < KPH * 16; i += 256) {
            int row = i >> 4, c4 = i & 15;
            uint4 v = *(const uint4*)(csrc + (size_t)row * NB_PAD + b0 + c4 * 4);
            *(uint4*)(&c_lds[row * TB + c4 * 4]) = v;
        }
        const int b = b0 + lane;
        float gbx = 0.f, gby = 0.f, gbz = 0.f;
        if (b < NA) {
            const float* g = geom + ((size_t)z * NA + b) * 3;
            gbx = g[0]; gby = g[1]; gbz = g[2];
        }
        __syncthreads();

        // basis (fp32) -> replicated h2 per a
        h2v u0[APW], u1[APW], u2[APW];
#pragma unroll
        for (int i = 0; i < APW; ++i) {
            const float* gp = &ga[(wave * APW + i) * 3];
            float dx = gbx - gp[0], dy = gby - gp[1], dz = gbz - gp[2];
            float r  = sqrtf(fmaf(dx, dx, fmaf(dy, dy, fmaf(dz, dz, 1e-12f))));
            float zz = r * (1.f / 1.5f);            // >= 0
            u0[i] = h2_splat(cos_half_pi(fminf(zz, 1.f)));
            u1[i] = h2_splat(cos_half_pi(fminf(fmaxf(zz - 1.f, -1.f), 1.f)));
            u2[i] = h2_splat(cos_half_pi(fminf(fmaxf(zz - 2.f, -1.f), 1.f)));
        }

        // kp loop over this half
#pragma unroll 5
        for (int kp = 0; kp < KPH; ++kp) {
            F4H u; u.f = wl[kp];
            h2v cb = c_lds[(kp << 6) | lane];
#pragma unroll
            for (int i = 0; i < APW; ++i) {
                h2v s = h2_fma(u0[i], u.h[0],
                        h2_fma(u1[i], u.h[1],
                        h2_fma(u2[i], u.h[2], u.h[3])));
                acc[i] = fdot2f(h2_max0(s), cb, acc[i]);
            }
        }
        __syncthreads();
    }

#pragma unroll
    for (int i = 0; i < APW; ++i) {
        float v = acc[i];
        for (int off = 32; off; off >>= 1) v += __shfl_xor(v, off);
        if (lane == 0) {
            int a = aBase + wave * APW + i;
            if (a < NA) feats_part[((size_t)kh * BATCH + z) * 288 + a] = v * RSQRT_N;
        }
    }
}

// ---------------------------------------------------------------------------
// Kernel 3: head, 256 thr per z. cz handled algebraically: h1[j] =
//   relu( sum_a fs[a]*W[a,j] + cz * sum_a W[a,j] + b[j] ), fc1 split 8x30.
// ---------------------------------------------------------------------------
__global__ void __launch_bounds__(256) head_kernel(
    const float* __restrict__ featsP,   // [2][B][288]
    const float* __restrict__ featIn,   // [B][286][23]
    const float* __restrict__ rb2,      // [23]
    const float* __restrict__ fc1W, const float* __restrict__ fc1b,
    const float* __restrict__ fc2W, const float* __restrict__ fc2b,
    const float* __restrict__ fc3W, const float* __restrict__ fc3b,
    float* __restrict__ out)            // [B]
{
    __shared__ float fsum[NA];
    __shared__ float ps[8][CIN];
    __shared__ float po[8][30], pw[8][30];
    __shared__ float czs;
    __shared__ float h1[30], hh2[10];

    const int z = blockIdx.x, tid = threadIdx.x;

    for (int a = tid; a < NA; a += 256)
        fsum[a] = featsP[z * 288 + a] + featsP[(BATCH + z) * 288 + a];

    if (tid < 8 * CIN) {                 // col-sums of featIn[z] over b, per j
        int j = tid % CIN, ch = tid / CIN;
        int b0 = ch * 36, b1 = (b0 + 36 < NA) ? b0 + 36 : NA;
        float s = 0.f;
        for (int b = b0; b < b1; ++b) s += featIn[((size_t)z * NA + b) * CIN + j];
        ps[ch][j] = s;
    }
    __syncthreads();
    if (tid < CIN) {
        float s = 0.f;
#pragma unroll
        for (int ch = 0; ch < 8; ++ch) s += ps[ch][tid];
        ps[0][tid] = s * rb2[tid];
    }
    __syncthreads();
    if (tid == 0) {
        float s = 0.f;
#pragma unroll
        for (int j = 0; j < CIN; ++j) s += ps[0][j];
        czs = s * (Y0F * RSQRT_N);
    }

    // fc1 partials: 8 a-chunks x 30 outputs
    if (tid < 240) {
        int j = tid % 30, ch = tid / 30;
        int a0 = ch * 36, a1 = (a0 + 36 < NA) ? a0 + 36 : NA;
        float o = 0.f, ws = 0.f;
        for (int a = a0; a < a1; ++a) {
            float w = fc1W[a * 30 + j];
            o  = fmaf(fsum[a], w, o);
            ws += w;
        }
        po[ch][j] = o; pw[ch][j] = ws;
    }
    __syncthreads();
    if (tid < 30) {
        float o = 0.f, ws = 0.f;
#pragma unroll
        for (int ch = 0; ch < 8; ++ch) { o += po[ch][tid]; ws += pw[ch][tid]; }
        h1[tid] = fmaxf(o + czs * ws + fc1b[tid], 0.f);
    }
    __syncthreads();
    if (tid < 10) {
        float v = fc2b[tid];
#pragma unroll
        for (int t = 0; t < 30; ++t) v = fmaf(h1[t], fc2W[t * 10 + tid], v);
        hh2[tid] = fmaxf(v, 0.f);
    }
    __syncthreads();
    if (tid == 0) {
        float v = fc3b[0];
#pragma unroll
        for (int t = 0; t < 10; ++t) v = fmaf(hh2[t], fc3W[t], v);
        out[z] = v;
    }
}

// ---------------------------------------------------------------------------
extern "C" void kernel_launch(void* const* d_in, const int* in_sizes, int n_in,
                              void* d_out, int out_size, void* d_ws, size_t ws_size,
                              hipStream_t stream) {
    const float* features = (const float*)d_in[1];
    const float* geometry = (const float*)d_in[2];
    const float* rW1  = (const float*)d_in[3];
    const float* rb1  = (const float*)d_in[4];
    const float* rW2  = (const float*)d_in[5];
    const float* rb2  = (const float*)d_in[6];
    const float* fc1W = (const float*)d_in[7];
    const float* fc1b = (const float*)d_in[8];
    const float* fc2W = (const float*)d_in[9];
    const float* fc2b = (const float*)d_in[10];
    const float* fc3W = (const float*)d_in[11];
    const float* fc3b = (const float*)d_in[12];

    char* ws = (char*)d_ws;
    float4* wpk    = (float4*)ws;                                    // 800 B
    h2v*    cbuf2  = (h2v*)(ws + 1024);                              // 2.048 MB
    float*  featsP = (float*)(ws + 1024 + (size_t)BATCH * NKP * NB_PAD * 4);

    float* out = (float*)d_out;

    prep_kernel<<<dim3(NTILE_B, BATCH, 2), 256, 0, stream>>>(
        features, rW2, rW1, rb1, cbuf2, wpk);
    pair_kernel<<<dim3(NTILE_A, BATCH, 2), 256, 0, stream>>>(
        geometry, cbuf2, wpk, featsP);
    head_kernel<<<BATCH, 256, 0, stream>>>(
        featsP, features, rb2, fc1W, fc1b, fc2W, fc2b, fc3W, fc3b, out);
}

// Round 6
// 143.357 us; speedup vs baseline: 1.3283x; 1.0073x over previous
//
#include <hip/hip_runtime.h>

#define NA      286   // atoms
#define CIN     23
#define NKH     100   // radial hidden width
#define NKP     50    // k-pairs
#define KPH     25    // k-pairs per half (k-split 2)
#define BATCH   32
#define NB_PAD  320
#define TB      64
#define ATILE   12    // a's per block (3 per wave, 4 waves)
#define APW     3
#define NTILE_A 24
#define NTILE_B 5
#define KQ_N    5     // prep kp-groups
#define KQ_SZ   10    // kp per prep block

#define Y0F      0.28209479177387814f   // 1/(2 sqrt(pi))
#define RSQRT_N  0.05913123960994873f   // 1/sqrt(286)

typedef _Float16 h2v __attribute__((ext_vector_type(2)));
union F4H { float4 f; h2v h[4]; };

__device__ __forceinline__ h2v h2_splat(float x) {
    _Float16 v = (_Float16)x;
    h2v r; r.x = v; r.y = v; return r;
}
__device__ __forceinline__ h2v h2_pack(float a, float b) {
    h2v r; r.x = (_Float16)a; r.y = (_Float16)b; return r;
}
__device__ __forceinline__ h2v h2_fma(h2v a, h2v b, h2v c) {
#if __has_builtin(__builtin_elementwise_fma)
    return __builtin_elementwise_fma(a, b, c);
#else
    return a * b + c;
#endif
}
__device__ __forceinline__ h2v h2_max0(h2v a) {
    h2v z; z.x = (_Float16)0.f; z.y = (_Float16)0.f;
#if __has_builtin(__builtin_elementwise_max)
    return __builtin_elementwise_max(a, z);
#else
    h2v r; r.x = a.x > z.x ? a.x : z.x; r.y = a.y > z.y ? a.y : z.y; return r;
#endif
}
__device__ __forceinline__ float fdot2f(h2v a, h2v b, float c) {
#if __has_builtin(__builtin_amdgcn_fdot2)
    return __builtin_amdgcn_fdot2(a, b, c, false);
#else
    return c + (float)a.x * (float)b.x + (float)a.y * (float)b.y;
#endif
}

// cos((pi/2)*x) for |x| <= 1; |err| <= ~3e-5
__device__ __forceinline__ float cos_half_pi(float x) {
    float t = 1.5707963267948966f * x;
    float w = t * t;
    return 1.f + w * (-0.5f + w * (4.16666667e-2f + w * (-1.38888889e-3f
               + w * 2.48015873e-5f)));
}

// ---------------------------------------------------------------------------
// Kernel 1: cbuf2[z][kp][b] = h2( Y0*dot(rW2[2kp],f[z,b]), Y0*dot(rW2[2kp+1],f[z,b]) )
// grid (5 bT, 32 z, 5 kQ); 256 thr; each block: 64 b x 10 kp.
// f-tile and rW2 slab staged via LDS (coalesced; 23 odd => conflict-free reads).
// Block (0,0,0) also packs wpk[kp] = {W1[0,k0|k1], W1[1,..], W1[2,..], b1[..]}
// ---------------------------------------------------------------------------
__global__ void __launch_bounds__(256) prep_kernel(
    const float* __restrict__ feat,   // [B][286][23]
    const float* __restrict__ rW2,    // [100][23]
    const float* __restrict__ rW1,    // [3][100]
    const float* __restrict__ rb1,    // [100]
    h2v* __restrict__ cbuf2,          // [B][50][320]
    float4* __restrict__ wpk)         // [50]
{
    __shared__ float flds[TB * CIN];          // 5888 B
    __shared__ float wlds[2 * KQ_SZ * CIN];   // 1840 B
    const int tid = threadIdx.x;
    const int bT  = blockIdx.x;
    const int z   = blockIdx.y;
    const int kQ  = blockIdx.z;

    if (bT == 0 && z == 0 && kQ == 0 && tid < NKP) {
        int k0 = 2 * tid, k1 = k0 + 1;
        F4H u;
        u.h[0] = h2_pack(rW1[k0],           rW1[k1]);
        u.h[1] = h2_pack(rW1[NKH + k0],     rW1[NKH + k1]);
        u.h[2] = h2_pack(rW1[2 * NKH + k0], rW1[2 * NKH + k1]);
        u.h[3] = h2_pack(rb1[k0],           rb1[k1]);
        wpk[tid] = u.f;
    }

    const int b0 = bT * TB;
    const int nf = ((NA - b0 < TB) ? (NA - b0) : TB) * CIN;
    const float* fsrc = feat + ((size_t)z * NA + b0) * CIN;     // contiguous
    for (int i = tid; i < TB * CIN; i += 256)
        flds[i] = (i < nf) ? fsrc[i] : 0.f;
    const float* wsrc = rW2 + (size_t)kQ * KQ_SZ * 2 * CIN;     // contiguous
    for (int i = tid; i < 2 * KQ_SZ * CIN; i += 256)
        wlds[i] = wsrc[i];
    __syncthreads();

    for (int i = tid; i < TB * KQ_SZ; i += 256) {
        int b   = i & 63;
        int kpl = i >> 6;               // wave-uniform per iteration
        const float* w0 = &wlds[(2 * kpl) * CIN];
        const float* w1 = &wlds[(2 * kpl + 1) * CIN];
        const float* fb = &flds[b * CIN];
        float s0 = 0.f, s1 = 0.f;
#pragma unroll
        for (int j = 0; j < CIN; ++j) {
            s0 = fmaf(fb[j], w0[j], s0);
            s1 = fmaf(fb[j], w1[j], s1);
        }
        int kp = kQ * KQ_SZ + kpl;
        cbuf2[((size_t)z * NKP + kp) * NB_PAD + b0 + b] = h2_pack(s0 * Y0F, s1 * Y0F);
    }
}

// ---------------------------------------------------------------------------
// Kernel 2: partial[kh][z][a] = sum_b sum_{kp in half} dot2(relu(u@W), c)
// grid (24, 32, 2); 256 thr (4 waves x 3 a); lane = b within 64-tile.
// NO LDS in the hot loop: W via block-uniform global read -> s_load_dwordx4
// (scalar cache), c via coalesced global_load_dword (L1-hot: 4 waves/block and
// 24 blocks per (z,kh) read the same 32 KB slab). Zero barriers in the k-loop.
// Per kp per wave: 1 VMEM + ~15 VALU (9 pk_fma + 3 pk_max + 3 dot2) for 2k x 3a.
// ---------------------------------------------------------------------------
__global__ void __launch_bounds__(256) pair_kernel(
    const float* __restrict__ geom,      // [B][286][3]
    const h2v* __restrict__ cbuf2,       // [B][50][320]
    const float4* __restrict__ wpk,      // [50]
    float* __restrict__ feats_part)      // [2][B][288]
{
    __shared__ float ga[ATILE * 3];

    const int tid   = threadIdx.x;
    const int z     = blockIdx.y;
    const int kh    = blockIdx.z;
    const int aBase = blockIdx.x * ATILE;

    if (tid < ATILE * 3) {
        int aa = aBase + tid / 3;
        int d  = tid - 3 * (tid / 3);
        ga[tid] = (aa < NA) ? geom[((size_t)z * NA + aa) * 3 + d] : 0.f;
    }
    __syncthreads();

    const int wave = tid >> 6;
    const int lane = tid & 63;

    float acc[APW] = {0.f, 0.f, 0.f};
    const h2v*    csrc = cbuf2 + ((size_t)z * NKP + kh * KPH) * NB_PAD;
    const float4* wsrc = wpk + kh * KPH;

    for (int t = 0; t < NTILE_B; ++t) {
        const int b = t * TB + lane;
        float gbx = 0.f, gby = 0.f, gbz = 0.f;
        if (b < NA) {
            const float* g = geom + ((size_t)z * NA + b) * 3;
            gbx = g[0]; gby = g[1]; gbz = g[2];
        }

        // basis (fp32) -> replicated h2 per a
        h2v u0[APW], u1[APW], u2[APW];
#pragma unroll
        for (int i = 0; i < APW; ++i) {
            const float* gp = &ga[(wave * APW + i) * 3];
            float dx = gbx - gp[0], dy = gby - gp[1], dz = gbz - gp[2];
            float r  = sqrtf(fmaf(dx, dx, fmaf(dy, dy, fmaf(dz, dz, 1e-12f))));
            float zz = r * (1.f / 1.5f);            // >= 0
            u0[i] = h2_splat(cos_half_pi(fminf(zz, 1.f)));
            u1[i] = h2_splat(cos_half_pi(fminf(fmaxf(zz - 1.f, -1.f), 1.f)));
            u2[i] = h2_splat(cos_half_pi(fminf(fmaxf(zz - 2.f, -1.f), 1.f)));
        }

        const h2v* cp = csrc + t * TB + lane;
#pragma unroll 5
        for (int kp = 0; kp < KPH; ++kp) {
            F4H u; u.f = wsrc[kp];              // block-uniform -> s_load_dwordx4
            h2v cb = cp[(size_t)kp * NB_PAD];   // coalesced global dword
#pragma unroll
            for (int i = 0; i < APW; ++i) {
                h2v s = h2_fma(u0[i], u.h[0],
                        h2_fma(u1[i], u.h[1],
                        h2_fma(u2[i], u.h[2], u.h[3])));
                acc[i] = fdot2f(h2_max0(s), cb, acc[i]);
            }
        }
    }

#pragma unroll
    for (int i = 0; i < APW; ++i) {
        float v = acc[i];
        for (int off = 32; off; off >>= 1) v += __shfl_xor(v, off);
        if (lane == 0) {
            int a = aBase + wave * APW + i;
            if (a < NA) feats_part[((size_t)kh * BATCH + z) * 288 + a] = v * RSQRT_N;
        }
    }
}

// ---------------------------------------------------------------------------
// Kernel 3: head, 256 thr per z. cz handled algebraically: h1[j] =
//   relu( sum_a fs[a]*W[a,j] + cz * sum_a W[a,j] + b[j] ), fc1 split 8x30.
// ---------------------------------------------------------------------------
__global__ void __launch_bounds__(256) head_kernel(
    const float* __restrict__ featsP,   // [2][B][288]
    const float* __restrict__ featIn,   // [B][286][23]
    const float* __restrict__ rb2,      // [23]
    const float* __restrict__ fc1W, const float* __restrict__ fc1b,
    const float* __restrict__ fc2W, const float* __restrict__ fc2b,
    const float* __restrict__ fc3W, const float* __restrict__ fc3b,
    float* __restrict__ out)            // [B]
{
    __shared__ float fsum[NA];
    __shared__ float ps[8][CIN];
    __shared__ float po[8][30], pw[8][30];
    __shared__ float czs;
    __shared__ float h1[30], hh2[10];

    const int z = blockIdx.x, tid = threadIdx.x;

    for (int a = tid; a < NA; a += 256)
        fsum[a] = featsP[z * 288 + a] + featsP[(BATCH + z) * 288 + a];

    if (tid < 8 * CIN) {                 // col-sums of featIn[z] over b, per j
        int j = tid % CIN, ch = tid / CIN;
        int b0 = ch * 36, b1 = (b0 + 36 < NA) ? b0 + 36 : NA;
        float s = 0.f;
        for (int b = b0; b < b1; ++b) s += featIn[((size_t)z * NA + b) * CIN + j];
        ps[ch][j] = s;
    }
    __syncthreads();
    if (tid < CIN) {
        float s = 0.f;
#pragma unroll
        for (int ch = 0; ch < 8; ++ch) s += ps[ch][tid];
        ps[0][tid] = s * rb2[tid];
    }
    __syncthreads();
    if (tid == 0) {
        float s = 0.f;
#pragma unroll
        for (int j = 0; j < CIN; ++j) s += ps[0][j];
        czs = s * (Y0F * RSQRT_N);
    }

    // fc1 partials: 8 a-chunks x 30 outputs
    if (tid < 240) {
        int j = tid % 30, ch = tid / 30;
        int a0 = ch * 36, a1 = (a0 + 36 < NA) ? a0 + 36 : NA;
        float o = 0.f, ws = 0.f;
        for (int a = a0; a < a1; ++a) {
            float w = fc1W[a * 30 + j];
            o  = fmaf(fsum[a], w, o);
            ws += w;
        }
        po[ch][j] = o; pw[ch][j] = ws;
    }
    __syncthreads();
    if (tid < 30) {
        float o = 0.f, ws = 0.f;
#pragma unroll
        for (int ch = 0; ch < 8; ++ch) { o += po[ch][tid]; ws += pw[ch][tid]; }
        h1[tid] = fmaxf(o + czs * ws + fc1b[tid], 0.f);
    }
    __syncthreads();
    if (tid < 10) {
        float v = fc2b[tid];
#pragma unroll
        for (int t = 0; t < 30; ++t) v = fmaf(h1[t], fc2W[t * 10 + tid], v);
        hh2[tid] = fmaxf(v, 0.f);
    }
    __syncthreads();
    if (tid == 0) {
        float v = fc3b[0];
#pragma unroll
        for (int t = 0; t < 10; ++t) v = fmaf(hh2[t], fc3W[t], v);
        out[z] = v;
    }
}

// ---------------------------------------------------------------------------
extern "C" void kernel_launch(void* const* d_in, const int* in_sizes, int n_in,
                              void* d_out, int out_size, void* d_ws, size_t ws_size,
                              hipStream_t stream) {
    const float* features = (const float*)d_in[1];
    const float* geometry = (const float*)d_in[2];
    const float* rW1  = (const float*)d_in[3];
    const float* rb1  = (const float*)d_in[4];
    const float* rW2  = (const float*)d_in[5];
    const float* rb2  = (const float*)d_in[6];
    const float* fc1W = (const float*)d_in[7];
    const float* fc1b = (const float*)d_in[8];
    const float* fc2W = (const float*)d_in[9];
    const float* fc2b = (const float*)d_in[10];
    const float* fc3W = (const float*)d_in[11];
    const float* fc3b = (const float*)d_in[12];

    char* ws = (char*)d_ws;
    float4* wpk    = (float4*)ws;                                    // 800 B
    h2v*    cbuf2  = (h2v*)(ws + 1024);                              // 2.048 MB
    float*  featsP = (float*)(ws + 1024 + (size_t)BATCH * NKP * NB_PAD * 4);

    float* out = (float*)d_out;

    prep_kernel<<<dim3(NTILE_B, BATCH, KQ_N), 256, 0, stream>>>(
        features, rW2, rW1, rb1, cbuf2, wpk);
    pair_kernel<<<dim3(NTILE_A, BATCH, 2), 256, 0, stream>>>(
        geometry, cbuf2, wpk, featsP);
    head_kernel<<<BATCH, 256, 0, stream>>>(
        featsP, features, rb2, fc1W, fc1b, fc2W, fc2b, fc3W, fc3b, out);
}

// Round 7
// 142.260 us; speedup vs baseline: 1.3385x; 1.0077x over previous
//
#include <hip/hip_runtime.h>

#define NA      286   // atoms
#define CIN     23
#define NKH     100   // radial hidden width
#define NKP     50    // k-pairs
#define KPH     25    // k-pairs per half (k-split 2)
#define BATCH   32
#define NB_PAD  320
#define TB      64
#define ATILE   12    // a's per block (3 per wave, 4 waves)
#define APW     3
#define NTILE_A 24
#define NTILE_B 5
#define KQ_N    5     // prep kp-groups
#define KQ_SZ   10    // kp per prep block

#define Y0F      0.28209479177387814f   // 1/(2 sqrt(pi))
#define RSQRT_N  0.05913123960994873f   // 1/sqrt(286)

typedef _Float16 h2v __attribute__((ext_vector_type(2)));
union F4H { float4 f; h2v h[4]; };

__device__ __forceinline__ h2v h2_splat(float x) {
    _Float16 v = (_Float16)x;
    h2v r; r.x = v; r.y = v; return r;
}
__device__ __forceinline__ h2v h2_pack(float a, float b) {
    h2v r; r.x = (_Float16)a; r.y = (_Float16)b; return r;
}
__device__ __forceinline__ h2v h2_fma(h2v a, h2v b, h2v c) {
#if __has_builtin(__builtin_elementwise_fma)
    return __builtin_elementwise_fma(a, b, c);
#else
    return a * b + c;
#endif
}
__device__ __forceinline__ h2v h2_max0(h2v a) {
    h2v z; z.x = (_Float16)0.f; z.y = (_Float16)0.f;
#if __has_builtin(__builtin_elementwise_max)
    return __builtin_elementwise_max(a, z);
#else
    h2v r; r.x = a.x > z.x ? a.x : z.x; r.y = a.y > z.y ? a.y : z.y; return r;
#endif
}
__device__ __forceinline__ float fdot2f(h2v a, h2v b, float c) {
#if __has_builtin(__builtin_amdgcn_fdot2)
    return __builtin_amdgcn_fdot2(a, b, c, false);
#else
    return c + (float)a.x * (float)b.x + (float)a.y * (float)b.y;
#endif
}

// cos((pi/2)*x) for |x| <= 1; |err| <= ~3e-5
__device__ __forceinline__ float cos_half_pi(float x) {
    float t = 1.5707963267948966f * x;
    float w = t * t;
    return 1.f + w * (-0.5f + w * (4.16666667e-2f + w * (-1.38888889e-3f
               + w * 2.48015873e-5f)));
}

// ---------------------------------------------------------------------------
// Kernel 1: cbuf2[z][kp][b] = h2( Y0*dot(rW2[2kp],f[z,b]), Y0*dot(rW2[2kp+1],f[z,b]) )
// grid (5 bT, 32 z, 5 kQ); 256 thr; each block: 64 b x 10 kp.
// ---------------------------------------------------------------------------
__global__ void __launch_bounds__(256) prep_kernel(
    const float* __restrict__ feat,   // [B][286][23]
    const float* __restrict__ rW2,    // [100][23]
    const float* __restrict__ rW1,    // [3][100]
    const float* __restrict__ rb1,    // [100]
    h2v* __restrict__ cbuf2,          // [B][50][320]
    float4* __restrict__ wpk)         // [50]
{
    __shared__ float flds[TB * CIN];          // 5888 B
    __shared__ float wlds[2 * KQ_SZ * CIN];   // 1840 B
    const int tid = threadIdx.x;
    const int bT  = blockIdx.x;
    const int z   = blockIdx.y;
    const int kQ  = blockIdx.z;

    if (bT == 0 && z == 0 && kQ == 0 && tid < NKP) {
        int k0 = 2 * tid, k1 = k0 + 1;
        F4H u;
        u.h[0] = h2_pack(rW1[k0],           rW1[k1]);
        u.h[1] = h2_pack(rW1[NKH + k0],     rW1[NKH + k1]);
        u.h[2] = h2_pack(rW1[2 * NKH + k0], rW1[2 * NKH + k1]);
        u.h[3] = h2_pack(rb1[k0],           rb1[k1]);
        wpk[tid] = u.f;
    }

    const int b0 = bT * TB;
    const int nf = ((NA - b0 < TB) ? (NA - b0) : TB) * CIN;
    const float* fsrc = feat + ((size_t)z * NA + b0) * CIN;     // contiguous
    for (int i = tid; i < TB * CIN; i += 256)
        flds[i] = (i < nf) ? fsrc[i] : 0.f;
    const float* wsrc = rW2 + (size_t)kQ * KQ_SZ * 2 * CIN;     // contiguous
    for (int i = tid; i < 2 * KQ_SZ * CIN; i += 256)
        wlds[i] = wsrc[i];
    __syncthreads();

    for (int i = tid; i < TB * KQ_SZ; i += 256) {
        int b   = i & 63;
        int kpl = i >> 6;               // wave-uniform per iteration
        const float* w0 = &wlds[(2 * kpl) * CIN];
        const float* w1 = &wlds[(2 * kpl + 1) * CIN];
        const float* fb = &flds[b * CIN];
        float s0 = 0.f, s1 = 0.f;
#pragma unroll
        for (int j = 0; j < CIN; ++j) {
            s0 = fmaf(fb[j], w0[j], s0);
            s1 = fmaf(fb[j], w1[j], s1);
        }
        int kp = kQ * KQ_SZ + kpl;
        cbuf2[((size_t)z * NKP + kp) * NB_PAD + b0 + b] = h2_pack(s0 * Y0F, s1 * Y0F);
    }
}

// ---------------------------------------------------------------------------
// Kernel 2: partial[kh][z][a] = sum_b sum_{kp in half} dot2(relu(u@W), c)
// grid (24, 32, 2); 256 thr (4 waves x 3 a); lane = b within 64-tile.
// One-shot LDS stage of the whole (z,kh) c-slab (32 KB, flat copy), single
// barrier, then a barrier-free k-loop: per kp = 1 ds_read_b32 (stride-1,
// conflict-free) + uniform s_load_dwordx4 (W, scalar pipe) + 15 VALU.
// kp fully unrolled (25) => 25 independent ds_reads in flight per tile.
// ---------------------------------------------------------------------------
__global__ void __launch_bounds__(256) pair_kernel(
    const float* __restrict__ geom,      // [B][286][3]
    const h2v* __restrict__ cbuf2,       // [B][50][320]
    const float4* __restrict__ wpk,      // [50]
    float* __restrict__ feats_part)      // [2][B][288]
{
    __shared__ h2v   c_all[KPH * NB_PAD];   // 32000 B
    __shared__ float ga[ATILE * 3];

    const int tid   = threadIdx.x;
    const int z     = blockIdx.y;
    const int kh    = blockIdx.z;
    const int aBase = blockIdx.x * ATILE;

    const h2v*    csrc = cbuf2 + ((size_t)z * NKP + kh * KPH) * NB_PAD;
    const float4* wsrc = wpk + kh * KPH;

    // flat 32 KB copy: global -> LDS, coalesced uint4
    {
        const uint4* s4 = (const uint4*)csrc;
        uint4*       d4 = (uint4*)c_all;
#pragma unroll
        for (int i = 0; i < (KPH * NB_PAD) / (4 * 256); ++i)    // 7 full rounds
            d4[i * 256 + tid] = s4[i * 256 + tid];
        int rem = ((KPH * NB_PAD) / 4) - ((KPH * NB_PAD) / (4 * 256)) * 256;
        if (tid < rem) {
            int base = ((KPH * NB_PAD) / (4 * 256)) * 256;
            d4[base + tid] = s4[base + tid];
        }
    }
    if (tid < ATILE * 3) {
        int aa = aBase + tid / 3;
        int d  = tid - 3 * (tid / 3);
        ga[tid] = (aa < NA) ? geom[((size_t)z * NA + aa) * 3 + d] : 0.f;
    }
    __syncthreads();

    const int wave = tid >> 6;
    const int lane = tid & 63;

    // this wave's a-geometry in registers
    float ax[APW], ay[APW], az[APW];
#pragma unroll
    for (int i = 0; i < APW; ++i) {
        ax[i] = ga[(wave * APW + i) * 3 + 0];
        ay[i] = ga[(wave * APW + i) * 3 + 1];
        az[i] = ga[(wave * APW + i) * 3 + 2];
    }

    float acc[APW] = {0.f, 0.f, 0.f};

    for (int t = 0; t < NTILE_B; ++t) {
        const int b = t * TB + lane;
        float gbx = 0.f, gby = 0.f, gbz = 0.f;
        if (b < NA) {
            const float* g = geom + ((size_t)z * NA + b) * 3;
            gbx = g[0]; gby = g[1]; gbz = g[2];
        }

        // basis (fp32) -> replicated h2 per a
        h2v u0[APW], u1[APW], u2[APW];
#pragma unroll
        for (int i = 0; i < APW; ++i) {
            float dx = gbx - ax[i], dy = gby - ay[i], dz = gbz - az[i];
            float r  = sqrtf(fmaf(dx, dx, fmaf(dy, dy, fmaf(dz, dz, 1e-12f))));
            float zz = r * (1.f / 1.5f);            // >= 0
            u0[i] = h2_splat(cos_half_pi(fminf(zz, 1.f)));
            u1[i] = h2_splat(cos_half_pi(fminf(fmaxf(zz - 1.f, -1.f), 1.f)));
            u2[i] = h2_splat(cos_half_pi(fminf(fmaxf(zz - 2.f, -1.f), 1.f)));
        }

        const h2v* cl = c_all + t * TB + lane;
#pragma unroll
        for (int kp = 0; kp < KPH; ++kp) {          // FULL unroll: 25 deep
            F4H u; u.f = wsrc[kp];                  // uniform -> s_load_dwordx4
            h2v cb = cl[kp * NB_PAD];               // ds_read_b32, conflict-free
#pragma unroll
            for (int i = 0; i < APW; ++i) {
                h2v s = h2_fma(u0[i], u.h[0],
                        h2_fma(u1[i], u.h[1],
                        h2_fma(u2[i], u.h[2], u.h[3])));
                acc[i] = fdot2f(h2_max0(s), cb, acc[i]);
            }
        }
    }

#pragma unroll
    for (int i = 0; i < APW; ++i) {
        float v = acc[i];
        for (int off = 32; off; off >>= 1) v += __shfl_xor(v, off);
        if (lane == 0) {
            int a = aBase + wave * APW + i;
            if (a < NA) feats_part[((size_t)kh * BATCH + z) * 288 + a] = v * RSQRT_N;
        }
    }
}

// ---------------------------------------------------------------------------
// Kernel 3: head, 256 thr per z. cz handled algebraically: h1[j] =
//   relu( sum_a fs[a]*W[a,j] + cz * sum_a W[a,j] + b[j] ), fc1 split 8x30.
// ---------------------------------------------------------------------------
__global__ void __launch_bounds__(256) head_kernel(
    const float* __restrict__ featsP,   // [2][B][288]
    const float* __restrict__ featIn,   // [B][286][23]
    const float* __restrict__ rb2,      // [23]
    const float* __restrict__ fc1W, const float* __restrict__ fc1b,
    const float* __restrict__ fc2W, const float* __restrict__ fc2b,
    const float* __restrict__ fc3W, const float* __restrict__ fc3b,
    float* __restrict__ out)            // [B]
{
    __shared__ float fsum[NA];
    __shared__ float ps[8][CIN];
    __shared__ float po[8][30], pw[8][30];
    __shared__ float czs;
    __shared__ float h1[30], hh2[10];

    const int z = blockIdx.x, tid = threadIdx.x;

    for (int a = tid; a < NA; a += 256)
        fsum[a] = featsP[z * 288 + a] + featsP[(BATCH + z) * 288 + a];

    if (tid < 8 * CIN) {                 // col-sums of featIn[z] over b, per j
        int j = tid % CIN, ch = tid / CIN;
        int b0 = ch * 36, b1 = (b0 + 36 < NA) ? b0 + 36 : NA;
        float s = 0.f;
        for (int b = b0; b < b1; ++b) s += featIn[((size_t)z * NA + b) * CIN + j];
        ps[ch][j] = s;
    }
    __syncthreads();
    if (tid < CIN) {
        float s = 0.f;
#pragma unroll
        for (int ch = 0; ch < 8; ++ch) s += ps[ch][tid];
        ps[0][tid] = s * rb2[tid];
    }
    __syncthreads();
    if (tid == 0) {
        float s = 0.f;
#pragma unroll
        for (int j = 0; j < CIN; ++j) s += ps[0][j];
        czs = s * (Y0F * RSQRT_N);
    }

    // fc1 partials: 8 a-chunks x 30 outputs
    if (tid < 240) {
        int j = tid % 30, ch = tid / 30;
        int a0 = ch * 36, a1 = (a0 + 36 < NA) ? a0 + 36 : NA;
        float o = 0.f, ws = 0.f;
        for (int a = a0; a < a1; ++a) {
            float w = fc1W[a * 30 + j];
            o  = fmaf(fsum[a], w, o);
            ws += w;
        }
        po[ch][j] = o; pw[ch][j] = ws;
    }
    __syncthreads();
    if (tid < 30) {
        float o = 0.f, ws = 0.f;
#pragma unroll
        for (int ch = 0; ch < 8; ++ch) { o += po[ch][tid]; ws += pw[ch][tid]; }
        h1[tid] = fmaxf(o + czs * ws + fc1b[tid], 0.f);
    }
    __syncthreads();
    if (tid < 10) {
        float v = fc2b[tid];
#pragma unroll
        for (int t = 0; t < 30; ++t) v = fmaf(h1[t], fc2W[t * 10 + tid], v);
        hh2[tid] = fmaxf(v, 0.f);
    }
    __syncthreads();
    if (tid == 0) {
        float v = fc3b[0];
#pragma unroll
        for (int t = 0; t < 10; ++t) v = fmaf(hh2[t], fc3W[t], v);
        out[z] = v;
    }
}

// ---------------------------------------------------------------------------
extern "C" void kernel_launch(void* const* d_in, const int* in_sizes, int n_in,
                              void* d_out, int out_size, void* d_ws, size_t ws_size,
                              hipStream_t stream) {
    const float* features = (const float*)d_in[1];
    const float* geometry = (const float*)d_in[2];
    const float* rW1  = (const float*)d_in[3];
    const float* rb1  = (const float*)d_in[4];
    const float* rW2  = (const float*)d_in[5];
    const float* rb2  = (const float*)d_in[6];
    const float* fc1W = (const float*)d_in[7];
    const float* fc1b = (const float*)d_in[8];
    const float* fc2W = (const float*)d_in[9];
    const float* fc2b = (const float*)d_in[10];
    const float* fc3W = (const float*)d_in[11];
    const float* fc3b = (const float*)d_in[12];

    char* ws = (char*)d_ws;
    float4* wpk    = (float4*)ws;                                    // 800 B
    h2v*    cbuf2  = (h2v*)(ws + 1024);                              // 2.048 MB
    float*  featsP = (float*)(ws + 1024 + (size_t)BATCH * NKP * NB_PAD * 4);

    float* out = (float*)d_out;

    prep_kernel<<<dim3(NTILE_B, BATCH, KQ_N), 256, 0, stream>>>(
        features, rW2, rW1, rb1, cbuf2, wpk);
    pair_kernel<<<dim3(NTILE_A, BATCH, 2), 256, 0, stream>>>(
        geometry, cbuf2, wpk, featsP);
    head_kernel<<<BATCH, 256, 0, stream>>>(
        featsP, features, rb2, fc1W, fc1b, fc2W, fc2b, fc3W, fc3b, out);
}

// Round 9
// 122.322 us; speedup vs baseline: 1.5567x; 1.1630x over previous
//
#include <hip/hip_runtime.h>

#define NA      286   // atoms
#define CIN     23
#define NKH     100   // radial hidden width
#define NKP     50    // k-pairs
#define BATCH   32
#define NB_PAD  320
#define TB      64
#define ATILE   12    // a's per block (3 per wave, 4 waves)
#define APW     3
#define NTILE_A 24
#define NTILE_B 5
#define KQ_N    5     // prep kp-groups
#define KQ_SZ   10    // kp per prep block

#define Y0F      0.28209479177387814f   // 1/(2 sqrt(pi))
#define RSQRT_N  0.05913123960994873f   // 1/sqrt(286)

typedef _Float16 h2v __attribute__((ext_vector_type(2)));
union F4H { float4 f; h2v h[4]; };

__device__ __forceinline__ h2v h2_splat(float x) {
    _Float16 v = (_Float16)x;
    h2v r; r.x = v; r.y = v; return r;
}
__device__ __forceinline__ h2v h2_pack(float a, float b) {
    h2v r; r.x = (_Float16)a; r.y = (_Float16)b; return r;
}
__device__ __forceinline__ h2v h2_fma(h2v a, h2v b, h2v c) {
#if __has_builtin(__builtin_elementwise_fma)
    return __builtin_elementwise_fma(a, b, c);
#else
    return a * b + c;
#endif
}
__device__ __forceinline__ h2v h2_max0(h2v a) {
    h2v z; z.x = (_Float16)0.f; z.y = (_Float16)0.f;
#if __has_builtin(__builtin_elementwise_max)
    return __builtin_elementwise_max(a, z);
#else
    h2v r; r.x = a.x > z.x ? a.x : z.x; r.y = a.y > z.y ? a.y : z.y; return r;
#endif
}
__device__ __forceinline__ float fdot2f(h2v a, h2v b, float c) {
#if __has_builtin(__builtin_amdgcn_fdot2)
    return __builtin_amdgcn_fdot2(a, b, c, false);
#else
    return c + (float)a.x * (float)b.x + (float)a.y * (float)b.y;
#endif
}

// cos((pi/2)*x) for |x| <= 1; |err| <= ~3e-5
__device__ __forceinline__ float cos_half_pi(float x) {
    float t = 1.5707963267948966f * x;
    float w = t * t;
    return 1.f + w * (-0.5f + w * (4.16666667e-2f + w * (-1.38888889e-3f
               + w * 2.48015873e-5f)));
}

// ---------------------------------------------------------------------------
// Kernel 1: cbuf2[z][kp][b] = h2( Y0*dot(rW2[2kp],f[z,b]), Y0*dot(rW2[2kp+1],f[z,b]) )
// grid (5 bT, 32 z, 5 kQ); 256 thr; each block: 64 b x 10 kp.
// ---------------------------------------------------------------------------
__global__ void __launch_bounds__(256) prep_kernel(
    const float* __restrict__ feat,   // [B][286][23]
    const float* __restrict__ rW2,    // [100][23]
    const float* __restrict__ rW1,    // [3][100]
    const float* __restrict__ rb1,    // [100]
    h2v* __restrict__ cbuf2,          // [B][50][320]
    float4* __restrict__ wpk)         // [50]
{
    __shared__ float flds[TB * CIN];          // 5888 B
    __shared__ float wlds[2 * KQ_SZ * CIN];   // 1840 B
    const int tid = threadIdx.x;
    const int bT  = blockIdx.x;
    const int z   = blockIdx.y;
    const int kQ  = blockIdx.z;

    if (bT == 0 && z == 0 && kQ == 0 && tid < NKP) {
        int k0 = 2 * tid, k1 = k0 + 1;
        F4H u;
        u.h[0] = h2_pack(rW1[k0],           rW1[k1]);
        u.h[1] = h2_pack(rW1[NKH + k0],     rW1[NKH + k1]);
        u.h[2] = h2_pack(rW1[2 * NKH + k0], rW1[2 * NKH + k1]);
        u.h[3] = h2_pack(rb1[k0],           rb1[k1]);
        wpk[tid] = u.f;
    }

    const int b0 = bT * TB;
    const int nf = ((NA - b0 < TB) ? (NA - b0) : TB) * CIN;
    const float* fsrc = feat + ((size_t)z * NA + b0) * CIN;     // contiguous
    for (int i = tid; i < TB * CIN; i += 256)
        flds[i] = (i < nf) ? fsrc[i] : 0.f;
    const float* wsrc = rW2 + (size_t)kQ * KQ_SZ * 2 * CIN;     // contiguous
    for (int i = tid; i < 2 * KQ_SZ * CIN; i += 256)
        wlds[i] = wsrc[i];
    __syncthreads();

    for (int i = tid; i < TB * KQ_SZ; i += 256) {
        int b   = i & 63;
        int kpl = i >> 6;               // wave-uniform per iteration
        const float* w0 = &wlds[(2 * kpl) * CIN];
        const float* w1 = &wlds[(2 * kpl + 1) * CIN];
        const float* fb = &flds[b * CIN];
        float s0 = 0.f, s1 = 0.f;
#pragma unroll
        for (int j = 0; j < CIN; ++j) {
            s0 = fmaf(fb[j], w0[j], s0);
            s1 = fmaf(fb[j], w1[j], s1);
        }
        int kp = kQ * KQ_SZ + kpl;
        cbuf2[((size_t)z * NKP + kp) * NB_PAD + b0 + b] = h2_pack(s0 * Y0F, s1 * Y0F);
    }
}

// ---------------------------------------------------------------------------
// Kernel 2: partial[bT][z][a] = sum_{b in tile} sum_kp dot2(relu(u@W), c)
// grid (24 aT, 32 z, 5 bT) = 3840 blocks = 15/CU -> 32 waves/CU resident.
// Block: 256 thr (4 waves x 3 a); lane = b within the 64-wide tile.
// Stage c[50 kp][64 b] (12.8 KB) + W (800 B) to LDS once; k-loop is pure-DS:
// per kp = 1 uniform ds_read_b128 (broadcast, conflict-free) + 1 stride-1
// ds_read_b32 + 15 VALU. Basis computed ONCE per (a,b) pair.
// __launch_bounds__(256,8): VGPR<=64 so 8 waves/SIMD materialize.
// ---------------------------------------------------------------------------
__global__ void __launch_bounds__(256, 8) pair_kernel(
    const float* __restrict__ geom,      // [B][286][3]
    const h2v* __restrict__ cbuf2,       // [B][50][320]
    const float4* __restrict__ wpk,      // [50]
    float* __restrict__ feats_part)      // [5][B][288]
{
    __shared__ h2v    c_lds[NKP * TB];   // 12800 B
    __shared__ float4 w_lds[NKP];        // 800 B
    __shared__ float  ga[ATILE * 3];

    const int tid   = threadIdx.x;
    const int z     = blockIdx.y;
    const int bT    = blockIdx.z;
    const int aBase = blockIdx.x * ATILE;

    // ---- stage: c-tile (50 rows x 16 uint4, coalesced) + W + a-geom ----
    {
        const uint4* s4 = (const uint4*)(cbuf2 + (size_t)z * NKP * NB_PAD + bT * TB);
        uint4*       d4 = (uint4*)c_lds;
        // 800 uint4 total; 256 thr -> 4 rounds (last partial).  [r8 bug: was 3]
#pragma unroll
        for (int r = 0; r < 4; ++r) {
            int i = r * 256 + tid;
            if (i < NKP * 16) {
                int row = i >> 4, col = i & 15;
                d4[i] = s4[(size_t)row * (NB_PAD / 4) + col];
            }
        }
    }
    if (tid < NKP) ((uint4*)w_lds)[tid] = ((const uint4*)wpk)[tid];
    if (tid >= 128 && tid < 128 + ATILE * 3) {
        int t  = tid - 128;
        int aa = aBase + t / 3;
        int d  = t - 3 * (t / 3);
        ga[t] = (aa < NA) ? geom[((size_t)z * NA + aa) * 3 + d] : 0.f;
    }
    __syncthreads();

    const int wave = tid >> 6;
    const int lane = tid & 63;

    // lane's b geometry
    const int b = bT * TB + lane;
    float gbx = 0.f, gby = 0.f, gbz = 0.f;
    if (b < NA) {
        const float* g = geom + ((size_t)z * NA + b) * 3;
        gbx = g[0]; gby = g[1]; gbz = g[2];
    }

    // basis, once per (a, b) pair
    h2v u0[APW], u1[APW], u2[APW];
#pragma unroll
    for (int i = 0; i < APW; ++i) {
        float axv = ga[(wave * APW + i) * 3 + 0];
        float ayv = ga[(wave * APW + i) * 3 + 1];
        float azv = ga[(wave * APW + i) * 3 + 2];
        float dx = gbx - axv, dy = gby - ayv, dz = gbz - azv;
        float r  = sqrtf(fmaf(dx, dx, fmaf(dy, dy, fmaf(dz, dz, 1e-12f))));
        float zz = r * (1.f / 1.5f);            // >= 0
        u0[i] = h2_splat(cos_half_pi(fminf(zz, 1.f)));
        u1[i] = h2_splat(cos_half_pi(fminf(fmaxf(zz - 1.f, -1.f), 1.f)));
        u2[i] = h2_splat(cos_half_pi(fminf(fmaxf(zz - 2.f, -1.f), 1.f)));
    }

    float acc[APW] = {0.f, 0.f, 0.f};
    const h2v* cl = c_lds + lane;

#pragma unroll 10
    for (int kp = 0; kp < NKP; ++kp) {
        F4H u; u.f = w_lds[kp];          // uniform addr -> broadcast, no conflict
        h2v cb = cl[kp * TB];            // stride-1 over lanes, conflict-free
#pragma unroll
        for (int i = 0; i < APW; ++i) {
            h2v s = h2_fma(u0[i], u.h[0],
                    h2_fma(u1[i], u.h[1],
                    h2_fma(u2[i], u.h[2], u.h[3])));
            acc[i] = fdot2f(h2_max0(s), cb, acc[i]);
        }
    }

#pragma unroll
    for (int i = 0; i < APW; ++i) {
        float v = acc[i];
        for (int off = 32; off; off >>= 1) v += __shfl_xor(v, off);
        if (lane == 0) {
            int a = aBase + wave * APW + i;
            if (a < NA)
                feats_part[((size_t)bT * BATCH + z) * 288 + a] = v * RSQRT_N;
        }
    }
}

// ---------------------------------------------------------------------------
// Kernel 3: head, 256 thr per z. Sums 5 b-tile partials; cz via weight-sums:
//   h1[j] = relu( sum_a fs[a]*W[a,j] + cz * sum_a W[a,j] + b[j] )
// ---------------------------------------------------------------------------
__global__ void __launch_bounds__(256) head_kernel(
    const float* __restrict__ featsP,   // [5][B][288]
    const float* __restrict__ featIn,   // [B][286][23]
    const float* __restrict__ rb2,      // [23]
    const float* __restrict__ fc1W, const float* __restrict__ fc1b,
    const float* __restrict__ fc2W, const float* __restrict__ fc2b,
    const float* __restrict__ fc3W, const float* __restrict__ fc3b,
    float* __restrict__ out)            // [B]
{
    __shared__ float fsum[NA];
    __shared__ float ps[8][CIN];
    __shared__ float po[8][30], pw[8][30];
    __shared__ float czs;
    __shared__ float h1[30], hh2[10];

    const int z = blockIdx.x, tid = threadIdx.x;

    for (int a = tid; a < NA; a += 256) {
        float s = 0.f;
#pragma unroll
        for (int bt = 0; bt < NTILE_B; ++bt)
            s += featsP[((size_t)bt * BATCH + z) * 288 + a];
        fsum[a] = s;
    }

    if (tid < 8 * CIN) {                 // col-sums of featIn[z] over b, per j
        int j = tid % CIN, ch = tid / CIN;
        int b0 = ch * 36, b1 = (b0 + 36 < NA) ? b0 + 36 : NA;
        float s = 0.f;
#pragma unroll 4
        for (int b = b0; b < b1; ++b) s += featIn[((size_t)z * NA + b) * CIN + j];
        ps[ch][j] = s;
    }
    __syncthreads();
    if (tid < CIN) {
        float s = 0.f;
#pragma unroll
        for (int ch = 0; ch < 8; ++ch) s += ps[ch][tid];
        ps[0][tid] = s * rb2[tid];
    }
    __syncthreads();
    if (tid == 0) {
        float s = 0.f;
#pragma unroll
        for (int j = 0; j < CIN; ++j) s += ps[0][j];
        czs = s * (Y0F * RSQRT_N);
    }

    // fc1 partials: 8 a-chunks x 30 outputs
    if (tid < 240) {
        int j = tid % 30, ch = tid / 30;
        int a0 = ch * 36, a1 = (a0 + 36 < NA) ? a0 + 36 : NA;
        float o = 0.f, ws = 0.f;
#pragma unroll 4
        for (int a = a0; a < a1; ++a) {
            float w = fc1W[a * 30 + j];
            o  = fmaf(fsum[a], w, o);
            ws += w;
        }
        po[ch][j] = o; pw[ch][j] = ws;
    }
    __syncthreads();
    if (tid < 30) {
        float o = 0.f, ws = 0.f;
#pragma unroll
        for (int ch = 0; ch < 8; ++ch) { o += po[ch][tid]; ws += pw[ch][tid]; }
        h1[tid] = fmaxf(o + czs * ws + fc1b[tid], 0.f);
    }
    __syncthreads();
    if (tid < 10) {
        float v = fc2b[tid];
#pragma unroll
        for (int t = 0; t < 30; ++t) v = fmaf(h1[t], fc2W[t * 10 + tid], v);
        hh2[tid] = fmaxf(v, 0.f);
    }
    __syncthreads();
    if (tid == 0) {
        float v = fc3b[0];
#pragma unroll
        for (int t = 0; t < 10; ++t) v = fmaf(hh2[t], fc3W[t], v);
        out[z] = v;
    }
}

// ---------------------------------------------------------------------------
extern "C" void kernel_launch(void* const* d_in, const int* in_sizes, int n_in,
                              void* d_out, int out_size, void* d_ws, size_t ws_size,
                              hipStream_t stream) {
    const float* features = (const float*)d_in[1];
    const float* geometry = (const float*)d_in[2];
    const float* rW1  = (const float*)d_in[3];
    const float* rb1  = (const float*)d_in[4];
    const float* rW2  = (const float*)d_in[5];
    const float* rb2  = (const float*)d_in[6];
    const float* fc1W = (const float*)d_in[7];
    const float* fc1b = (const float*)d_in[8];
    const float* fc2W = (const float*)d_in[9];
    const float* fc2b = (const float*)d_in[10];
    const float* fc3W = (const float*)d_in[11];
    const float* fc3b = (const float*)d_in[12];

    char* ws = (char*)d_ws;
    float4* wpk    = (float4*)ws;                                    // 800 B
    h2v*    cbuf2  = (h2v*)(ws + 1024);                              // 2.048 MB
    float*  featsP = (float*)(ws + 1024 + (size_t)BATCH * NKP * NB_PAD * 4);
                                                                     // 5*32*288 f32

    float* out = (float*)d_out;

    prep_kernel<<<dim3(NTILE_B, BATCH, KQ_N), 256, 0, stream>>>(
        features, rW2, rW1, rb1, cbuf2, wpk);
    pair_kernel<<<dim3(NTILE_A, BATCH, NTILE_B), 256, 0, stream>>>(
        geometry, cbuf2, wpk, featsP);
    head_kernel<<<BATCH, 256, 0, stream>>>(
        featsP, features, rb2, fc1W, fc1b, fc2W, fc2b, fc3W, fc3b, out);
}

// Round 10
// 122.278 us; speedup vs baseline: 1.5573x; 1.0004x over previous
//
#include <hip/hip_runtime.h>

#define NA      286   // atoms
#define CIN     23
#define NKH     100   // radial hidden width
#define NKP     50    // k-pairs
#define BATCH   32
#define NB_PAD  320
#define TB      64
#define ATILE   12    // a's per block (3 per wave, 4 waves)
#define APW     3
#define NTILE_A 24
#define NTILE_B 5
#define KQ_N    5     // prep kp-groups
#define KQ_SZ   10    // kp per prep block

#define Y0F      0.28209479177387814f   // 1/(2 sqrt(pi))
#define RSQRT_N  0.05913123960994873f   // 1/sqrt(286)

typedef _Float16 h2v __attribute__((ext_vector_type(2)));
union F4H { float4 f; h2v h[4]; };

__device__ __forceinline__ h2v h2_splat(float x) {
    _Float16 v = (_Float16)x;
    h2v r; r.x = v; r.y = v; return r;
}
__device__ __forceinline__ h2v h2_pack(float a, float b) {
    h2v r; r.x = (_Float16)a; r.y = (_Float16)b; return r;
}
__device__ __forceinline__ h2v h2_fma(h2v a, h2v b, h2v c) {
#if __has_builtin(__builtin_elementwise_fma)
    return __builtin_elementwise_fma(a, b, c);
#else
    return a * b + c;
#endif
}
__device__ __forceinline__ h2v h2_max0(h2v a) {
    h2v z; z.x = (_Float16)0.f; z.y = (_Float16)0.f;
#if __has_builtin(__builtin_elementwise_max)
    return __builtin_elementwise_max(a, z);
#else
    h2v r; r.x = a.x > z.x ? a.x : z.x; r.y = a.y > z.y ? a.y : z.y; return r;
#endif
}
__device__ __forceinline__ float fdot2f(h2v a, h2v b, float c) {
#if __has_builtin(__builtin_amdgcn_fdot2)
    return __builtin_amdgcn_fdot2(a, b, c, false);
#else
    return c + (float)a.x * (float)b.x + (float)a.y * (float)b.y;
#endif
}

// cos((pi/2)*x) for |x| <= 1; |err| <= ~3e-5
__device__ __forceinline__ float cos_half_pi(float x) {
    float t = 1.5707963267948966f * x;
    float w = t * t;
    return 1.f + w * (-0.5f + w * (4.16666667e-2f + w * (-1.38888889e-3f
               + w * 2.48015873e-5f)));
}

// ---------------------------------------------------------------------------
// Kernel 1: cbuf2[z][kp][b] = h2( Y0*dot(rW2[2kp],f[z,b]), Y0*dot(rW2[2kp+1],f[z,b]) )
// grid (5 bT, 32 z, 5 kQ); 256 thr; each block: 64 b x 10 kp.
// kQ==0 blocks additionally reduce their f-tile to per-j column sums
// (colsum[z][bT][23]) so the head never touches featIn (strided) again.
// ---------------------------------------------------------------------------
__global__ void __launch_bounds__(256) prep_kernel(
    const float* __restrict__ feat,   // [B][286][23]
    const float* __restrict__ rW2,    // [100][23]
    const float* __restrict__ rW1,    // [3][100]
    const float* __restrict__ rb1,    // [100]
    h2v* __restrict__ cbuf2,          // [B][50][320]
    float4* __restrict__ wpk,         // [50]
    float* __restrict__ colsum)       // [B][5][23]
{
    __shared__ float flds[TB * CIN];          // 5888 B
    __shared__ float wlds[2 * KQ_SZ * CIN];   // 1840 B
    __shared__ float csum[8][CIN];            // 736 B
    const int tid = threadIdx.x;
    const int bT  = blockIdx.x;
    const int z   = blockIdx.y;
    const int kQ  = blockIdx.z;

    if (bT == 0 && z == 0 && kQ == 0 && tid < NKP) {
        int k0 = 2 * tid, k1 = k0 + 1;
        F4H u;
        u.h[0] = h2_pack(rW1[k0],           rW1[k1]);
        u.h[1] = h2_pack(rW1[NKH + k0],     rW1[NKH + k1]);
        u.h[2] = h2_pack(rW1[2 * NKH + k0], rW1[2 * NKH + k1]);
        u.h[3] = h2_pack(rb1[k0],           rb1[k1]);
        wpk[tid] = u.f;
    }

    const int b0 = bT * TB;
    const int nf = ((NA - b0 < TB) ? (NA - b0) : TB) * CIN;
    const float* fsrc = feat + ((size_t)z * NA + b0) * CIN;     // contiguous
    for (int i = tid; i < TB * CIN; i += 256)
        flds[i] = (i < nf) ? fsrc[i] : 0.f;
    const float* wsrc = rW2 + (size_t)kQ * KQ_SZ * 2 * CIN;     // contiguous
    for (int i = tid; i < 2 * KQ_SZ * CIN; i += 256)
        wlds[i] = wsrc[i];
    __syncthreads();

    if (kQ == 0) {          // uniform branch (blockIdx.z) — barriers safe
        if (tid < 8 * CIN) {
            int j = tid % CIN, ch = tid / CIN;
            float s = 0.f;
#pragma unroll
            for (int bb = 0; bb < 8; ++bb) s += flds[(ch * 8 + bb) * CIN + j];
            csum[ch][j] = s;
        }
        __syncthreads();
        if (tid < CIN) {
            float s = 0.f;
#pragma unroll
            for (int ch = 0; ch < 8; ++ch) s += csum[ch][tid];
            colsum[((size_t)z * NTILE_B + bT) * CIN + tid] = s;
        }
    }

    for (int i = tid; i < TB * KQ_SZ; i += 256) {
        int b   = i & 63;
        int kpl = i >> 6;               // wave-uniform per iteration
        const float* w0 = &wlds[(2 * kpl) * CIN];
        const float* w1 = &wlds[(2 * kpl + 1) * CIN];
        const float* fb = &flds[b * CIN];
        float s0 = 0.f, s1 = 0.f;
#pragma unroll
        for (int j = 0; j < CIN; ++j) {
            s0 = fmaf(fb[j], w0[j], s0);
            s1 = fmaf(fb[j], w1[j], s1);
        }
        int kp = kQ * KQ_SZ + kpl;
        cbuf2[((size_t)z * NKP + kp) * NB_PAD + b0 + b] = h2_pack(s0 * Y0F, s1 * Y0F);
    }
}

// ---------------------------------------------------------------------------
// Kernel 2: partial[bT][z][a] = sum_{b in tile} sum_kp dot2(relu(u@W), c)
// grid (24 aT, 32 z, 5 bT) = 3840 blocks = 15/CU -> 32 waves/CU resident.
// Stage c[50 kp][64 b] (12.8 KB) + W (800 B) to LDS once; pure-DS k-loop:
// per kp = 1 uniform ds_read_b128 (broadcast) + 1 stride-1 ds_read_b32 + 15 VALU.
// Basis computed ONCE per (a,b). __launch_bounds__(256,8): VGPR<=64.
// [r9 measured: passed, absmax 0.0, 44 VGPR — unchanged this round]
// ---------------------------------------------------------------------------
__global__ void __launch_bounds__(256, 8) pair_kernel(
    const float* __restrict__ geom,      // [B][286][3]
    const h2v* __restrict__ cbuf2,       // [B][50][320]
    const float4* __restrict__ wpk,      // [50]
    float* __restrict__ feats_part)      // [5][B][288]
{
    __shared__ h2v    c_lds[NKP * TB];   // 12800 B
    __shared__ float4 w_lds[NKP];        // 800 B
    __shared__ float  ga[ATILE * 3];

    const int tid   = threadIdx.x;
    const int z     = blockIdx.y;
    const int bT    = blockIdx.z;
    const int aBase = blockIdx.x * ATILE;

    // ---- stage: c-tile (50 rows x 16 uint4, coalesced) + W + a-geom ----
    {
        const uint4* s4 = (const uint4*)(cbuf2 + (size_t)z * NKP * NB_PAD + bT * TB);
        uint4*       d4 = (uint4*)c_lds;
#pragma unroll
        for (int r = 0; r < 4; ++r) {        // 800 uint4 over 256 thr
            int i = r * 256 + tid;
            if (i < NKP * 16) {
                int row = i >> 4, col = i & 15;
                d4[i] = s4[(size_t)row * (NB_PAD / 4) + col];
            }
        }
    }
    if (tid < NKP) ((uint4*)w_lds)[tid] = ((const uint4*)wpk)[tid];
    if (tid >= 128 && tid < 128 + ATILE * 3) {
        int t  = tid - 128;
        int aa = aBase + t / 3;
        int d  = t - 3 * (t / 3);
        ga[t] = (aa < NA) ? geom[((size_t)z * NA + aa) * 3 + d] : 0.f;
    }
    __syncthreads();

    const int wave = tid >> 6;
    const int lane = tid & 63;

    const int b = bT * TB + lane;
    float gbx = 0.f, gby = 0.f, gbz = 0.f;
    if (b < NA) {
        const float* g = geom + ((size_t)z * NA + b) * 3;
        gbx = g[0]; gby = g[1]; gbz = g[2];
    }

    // basis, once per (a, b) pair
    h2v u0[APW], u1[APW], u2[APW];
#pragma unroll
    for (int i = 0; i < APW; ++i) {
        float axv = ga[(wave * APW + i) * 3 + 0];
        float ayv = ga[(wave * APW + i) * 3 + 1];
        float azv = ga[(wave * APW + i) * 3 + 2];
        float dx = gbx - axv, dy = gby - ayv, dz = gbz - azv;
        float r  = sqrtf(fmaf(dx, dx, fmaf(dy, dy, fmaf(dz, dz, 1e-12f))));
        float zz = r * (1.f / 1.5f);            // >= 0
        u0[i] = h2_splat(cos_half_pi(fminf(zz, 1.f)));
        u1[i] = h2_splat(cos_half_pi(fminf(fmaxf(zz - 1.f, -1.f), 1.f)));
        u2[i] = h2_splat(cos_half_pi(fminf(fmaxf(zz - 2.f, -1.f), 1.f)));
    }

    float acc[APW] = {0.f, 0.f, 0.f};
    const h2v* cl = c_lds + lane;

#pragma unroll 10
    for (int kp = 0; kp < NKP; ++kp) {
        F4H u; u.f = w_lds[kp];          // uniform addr -> broadcast, no conflict
        h2v cb = cl[kp * TB];            // stride-1 over lanes, conflict-free
#pragma unroll
        for (int i = 0; i < APW; ++i) {
            h2v s = h2_fma(u0[i], u.h[0],
                    h2_fma(u1[i], u.h[1],
                    h2_fma(u2[i], u.h[2], u.h[3])));
            acc[i] = fdot2f(h2_max0(s), cb, acc[i]);
        }
    }

#pragma unroll
    for (int i = 0; i < APW; ++i) {
        float v = acc[i];
        for (int off = 32; off; off >>= 1) v += __shfl_xor(v, off);
        if (lane == 0) {
            int a = aBase + wave * APW + i;
            if (a < NA)
                feats_part[((size_t)bT * BATCH + z) * 288 + a] = v * RSQRT_N;
        }
    }
}

// ---------------------------------------------------------------------------
// Kernel 3: head, 256 thr per z. Sums 5 b-tile partials; cz from precomputed
// colsum (115 contiguous floats) instead of a strided featIn pass:
//   h1[j] = relu( sum_a fs[a]*W[a,j] + cz * sum_a W[a,j] + b[j] )
// ---------------------------------------------------------------------------
__global__ void __launch_bounds__(256) head_kernel(
    const float* __restrict__ featsP,   // [5][B][288]
    const float* __restrict__ colsum,   // [B][5][23]
    const float* __restrict__ rb2,      // [23]
    const float* __restrict__ fc1W, const float* __restrict__ fc1b,
    const float* __restrict__ fc2W, const float* __restrict__ fc2b,
    const float* __restrict__ fc3W, const float* __restrict__ fc3b,
    float* __restrict__ out)            // [B]
{
    __shared__ float fsum[NA];
    __shared__ float ps0[CIN];
    __shared__ float po[8][30], pw[8][30];
    __shared__ float czs;
    __shared__ float h1[30], hh2[10];

    const int z = blockIdx.x, tid = threadIdx.x;

    for (int a = tid; a < NA; a += 256) {
        float s = 0.f;
#pragma unroll
        for (int bt = 0; bt < NTILE_B; ++bt)
            s += featsP[((size_t)bt * BATCH + z) * 288 + a];
        fsum[a] = s;
    }

    if (tid < CIN) {
        float s = 0.f;
#pragma unroll
        for (int bt = 0; bt < NTILE_B; ++bt)
            s += colsum[((size_t)z * NTILE_B + bt) * CIN + tid];
        ps0[tid] = s * rb2[tid];
    }
    __syncthreads();
    if (tid == 0) {
        float s = 0.f;
#pragma unroll
        for (int j = 0; j < CIN; ++j) s += ps0[j];
        czs = s * (Y0F * RSQRT_N);
    }

    // fc1 partials: 8 a-chunks x 30 outputs
    if (tid < 240) {
        int j = tid % 30, ch = tid / 30;
        int a0 = ch * 36, a1 = (a0 + 36 < NA) ? a0 + 36 : NA;
        float o = 0.f, ws = 0.f;
#pragma unroll 4
        for (int a = a0; a < a1; ++a) {
            float w = fc1W[a * 30 + j];
            o  = fmaf(fsum[a], w, o);
            ws += w;
        }
        po[ch][j] = o; pw[ch][j] = ws;
    }
    __syncthreads();
    if (tid < 30) {
        float o = 0.f, ws = 0.f;
#pragma unroll
        for (int ch = 0; ch < 8; ++ch) { o += po[ch][tid]; ws += pw[ch][tid]; }
        h1[tid] = fmaxf(o + czs * ws + fc1b[tid], 0.f);
    }
    __syncthreads();
    if (tid < 10) {
        float v = fc2b[tid];
#pragma unroll
        for (int t = 0; t < 30; ++t) v = fmaf(h1[t], fc2W[t * 10 + tid], v);
        hh2[tid] = fmaxf(v, 0.f);
    }
    __syncthreads();
    if (tid == 0) {
        float v = fc3b[0];
#pragma unroll
        for (int t = 0; t < 10; ++t) v = fmaf(hh2[t], fc3W[t], v);
        out[z] = v;
    }
}

// ---------------------------------------------------------------------------
extern "C" void kernel_launch(void* const* d_in, const int* in_sizes, int n_in,
                              void* d_out, int out_size, void* d_ws, size_t ws_size,
                              hipStream_t stream) {
    const float* features = (const float*)d_in[1];
    const float* geometry = (const float*)d_in[2];
    const float* rW1  = (const float*)d_in[3];
    const float* rb1  = (const float*)d_in[4];
    const float* rW2  = (const float*)d_in[5];
    const float* rb2  = (const float*)d_in[6];
    const float* fc1W = (const float*)d_in[7];
    const float* fc1b = (const float*)d_in[8];
    const float* fc2W = (const float*)d_in[9];
    const float* fc2b = (const float*)d_in[10];
    const float* fc3W = (const float*)d_in[11];
    const float* fc3b = (const float*)d_in[12];

    char* ws = (char*)d_ws;
    float4* wpk    = (float4*)ws;                                    // 800 B
    h2v*    cbuf2  = (h2v*)(ws + 1024);                              // 2.048 MB
    float*  featsP = (float*)(ws + 1024 + (size_t)BATCH * NKP * NB_PAD * 4);
    float*  colsum = featsP + (size_t)NTILE_B * BATCH * 288;         // 32*5*23 f32

    float* out = (float*)d_out;

    prep_kernel<<<dim3(NTILE_B, BATCH, KQ_N), 256, 0, stream>>>(
        features, rW2, rW1, rb1, cbuf2, wpk, colsum);
    pair_kernel<<<dim3(NTILE_A, BATCH, NTILE_B), 256, 0, stream>>>(
        geometry, cbuf2, wpk, featsP);
    head_kernel<<<BATCH, 256, 0, stream>>>(
        featsP, colsum, rb2, fc1W, fc1b, fc2W, fc2b, fc3W, fc3b, out);
}